// Round 3
// baseline (153.703 us; speedup 1.0000x reference)
//
#include <hip/hip_runtime.h>

#define D_ 8
#define B_ 32
#define PRE_ 1024
#define POST_ 1024

// exp(-1/10), exp(-1/20), exp(-1/15)
#define ALPHA_P 0.90483741803595952f
#define ALPHA_D 0.95122942450071400f
#define ALPHA_X 0.93550698503161731f

#define BCHUNK 8                          // b values per main block
#define NBC    (B_ / BCHUNK)              // 4 b-chunks
#define NMAIN  (PRE_ * NBC)               // 4096 main blocks
#define NFILT  (((D_*B_*PRE_)/4 + 2*((B_*POST_)/4)) / 256)   // 320 filter blocks

typedef float f32x4 __attribute__((ext_vector_type(4)));

// Main blocks (bid < NMAIN): e = bid >> 2, bc = bid & 3.
//   Same-e blocks are CONSECUTIVE in dispatch order -> co-resident across 4 XCDs
//   -> dmap[.,e,.] is fetched from HBM once; L3 serves the replicas.
//   W is loaded non-temporally and out/W_new stored non-temporally so the
//   streaming ~400 MB doesn't evict the reused dmap/A_p/A_d/wmax.
// Tail blocks: elementwise exponential filters.
__global__ __launch_bounds__(256) void clopath_fused(
    const float* __restrict__ W,
    const float* __restrict__ dmap,
    const float* __restrict__ A_p,
    const float* __restrict__ A_d,
    const float* __restrict__ wmax,
    const float* __restrict__ xbar_pre,
    const float* __restrict__ Xd,
    const float* __restrict__ Xpost,
    const float* __restrict__ Vpost,
    const float* __restrict__ u_pot,
    const float* __restrict__ u_dep,
    float* __restrict__ out,       // output 0: copy of W
    float* __restrict__ W_new,     // output 1
    float* __restrict__ xbar_new,  // output 2
    float* __restrict__ u_pot_new, // output 3
    float* __restrict__ u_dep_new) // output 4
{
    const int bid = blockIdx.x;
    const int tid = threadIdx.x;

    if (bid < NMAIN) {
        const int e  = bid >> 2;           // 0..1023 (consecutive bids share e)
        const int bc = bid & (NBC - 1);    // 0..3
        const int b0 = bc * BCHUNK;        // first b of this block
        const int o  = tid << 2;           // float4 of POST

        // Stage the 64 block-uniform scalars xbar_pre[d, b0+bi, e], Xd[d, b0+bi, e]
        __shared__ float xb_lds[D_ * BCHUNK];
        __shared__ float xd_lds[D_ * BCHUNK];
        if (tid < D_ * BCHUNK) {
            const int d  = tid >> 3;
            const int bi = tid & (BCHUNK - 1);
            const size_t idx = ((size_t)(d * B_ + b0 + bi)) * PRE_ + e;
            xb_lds[tid] = xbar_pre[idx];
            xd_lds[tid] = Xd[idx];
        }
        __syncthreads();

        // Preload dmap rows and per-(e,o) factors into registers (cached reads)
        float dmv[D_][4];
        #pragma unroll
        for (int d = 0; d < D_; ++d) {
            f32x4 t = *reinterpret_cast<const f32x4*>(
                dmap + ((size_t)(d * PRE_ + e) * POST_ + o));
            dmv[d][0] = t.x; dmv[d][1] = t.y; dmv[d][2] = t.z; dmv[d][3] = t.w;
        }
        float apv[4], adv[4], wmv[4];
        {
            f32x4 a = *reinterpret_cast<const f32x4*>(A_p  + ((size_t)e * POST_ + o));
            apv[0] = a.x; apv[1] = a.y; apv[2] = a.z; apv[3] = a.w;
            f32x4 b = *reinterpret_cast<const f32x4*>(A_d  + ((size_t)e * POST_ + o));
            adv[0] = b.x; adv[1] = b.y; adv[2] = b.z; adv[3] = b.w;
            f32x4 c = *reinterpret_cast<const f32x4*>(wmax + ((size_t)e * POST_ + o));
            wmv[0] = c.x; wmv[1] = c.y; wmv[2] = c.z; wmv[3] = c.w;
        }

        #pragma unroll 4
        for (int bi = 0; bi < BCHUNK; ++bi) {
            const int b = b0 + bi;
            const size_t wi = ((size_t)(b * PRE_ + e)) * POST_ + o;
            const size_t go = (size_t)b * POST_ + o;

            // W is read-once: non-temporal (don't pollute L2/L3)
            f32x4 w4  = __builtin_nontemporal_load(
                            reinterpret_cast<const f32x4*>(W + wi));
            f32x4 xp4 = *reinterpret_cast<const f32x4*>(Xpost + go);
            f32x4 up4 = *reinterpret_cast<const f32x4*>(u_pot + go);
            f32x4 ud4 = *reinterpret_cast<const f32x4*>(u_dep + go);

            float sp[4] = {0.f, 0.f, 0.f, 0.f};
            float sd[4] = {0.f, 0.f, 0.f, 0.f};
            #pragma unroll
            for (int d = 0; d < D_; ++d) {
                const float xb = xb_lds[d * BCHUNK + bi];   // uniform -> broadcast
                const float xd = xd_lds[d * BCHUNK + bi];
                #pragma unroll
                for (int j = 0; j < 4; ++j) {
                    sp[j] = fmaf(xb, dmv[d][j], sp[j]);
                    sd[j] = fmaf(xd, dmv[d][j], sd[j]);
                }
            }

            f32x4 nv;
            #pragma unroll
            for (int j = 0; j < 4; ++j) {
                const float wvj = (j == 0) ? w4.x : (j == 1) ? w4.y : (j == 2) ? w4.z : w4.w;
                const float xpj = (j == 0) ? xp4.x : (j == 1) ? xp4.y : (j == 2) ? xp4.z : xp4.w;
                const float upj = (j == 0) ? up4.x : (j == 1) ? up4.y : (j == 2) ? up4.z : up4.w;
                const float udj = (j == 0) ? ud4.x : (j == 1) ? ud4.y : (j == 2) ? ud4.z : ud4.w;
                const float gp = xpj * fmaxf(upj, 0.f);   // Xpost * relu(u_pot)
                const float gd = fmaxf(udj, 0.f);         // relu(u_dep)
                float wn = wvj + sp[j] * apv[j] * gp - sd[j] * adv[j] * gd;
                wn = fminf(wmv[j], fmaxf(wn, 0.f));
                nv[j] = wn;
            }
            // streaming outputs: non-temporal stores
            __builtin_nontemporal_store(w4, reinterpret_cast<f32x4*>(out   + wi));
            __builtin_nontemporal_store(nv, reinterpret_cast<f32x4*>(W_new + wi));
        }
    } else {
        // ---- filter tail: elementwise exponential filters ----
        const int i = (bid - NMAIN) * 256 + tid;   // float4 index
        const int NX = (D_ * B_ * PRE_) / 4;       // 65536
        const int NU = (B_ * POST_) / 4;           // 8192

        if (i < NX) {
            f32x4 a = *reinterpret_cast<const f32x4*>(xbar_pre + (size_t)i * 4);
            f32x4 b = *reinterpret_cast<const f32x4*>(Xd       + (size_t)i * 4);
            f32x4 r = ALPHA_X * a + (1.0f - ALPHA_X) * b;
            __builtin_nontemporal_store(r, reinterpret_cast<f32x4*>(xbar_new + (size_t)i * 4));
        } else if (i < NX + NU) {
            const int j = i - NX;
            f32x4 a = *reinterpret_cast<const f32x4*>(u_pot + (size_t)j * 4);
            f32x4 b = *reinterpret_cast<const f32x4*>(Vpost + (size_t)j * 4);
            f32x4 r = ALPHA_P * a + (1.0f - ALPHA_P) * b;
            __builtin_nontemporal_store(r, reinterpret_cast<f32x4*>(u_pot_new + (size_t)j * 4));
        } else {
            const int j = i - NX - NU;
            f32x4 a = *reinterpret_cast<const f32x4*>(u_dep + (size_t)j * 4);
            f32x4 b = *reinterpret_cast<const f32x4*>(Vpost + (size_t)j * 4);
            f32x4 r = ALPHA_D * a + (1.0f - ALPHA_D) * b;
            __builtin_nontemporal_store(r, reinterpret_cast<f32x4*>(u_dep_new + (size_t)j * 4));
        }
    }
}

extern "C" void kernel_launch(void* const* d_in, const int* in_sizes, int n_in,
                              void* d_out, int out_size, void* d_ws, size_t ws_size,
                              hipStream_t stream) {
    const float* Xd       = (const float*)d_in[0];
    const float* Xpost    = (const float*)d_in[1];
    const float* Vpost    = (const float*)d_in[2];
    const float* W        = (const float*)d_in[3];
    const float* xbar_pre = (const float*)d_in[4];
    const float* u_pot    = (const float*)d_in[5];
    const float* u_dep    = (const float*)d_in[6];
    const float* dmap     = (const float*)d_in[7];
    const float* A_p      = (const float*)d_in[8];
    const float* A_d      = (const float*)d_in[9];
    const float* wmax     = (const float*)d_in[10];

    float* out        = (float*)d_out;
    float* W_new      = out + (size_t)B_ * PRE_ * POST_;
    float* xbar_new   = W_new + (size_t)B_ * PRE_ * POST_;
    float* u_pot_new  = xbar_new + (size_t)D_ * B_ * PRE_;
    float* u_dep_new  = u_pot_new + (size_t)B_ * POST_;

    clopath_fused<<<NMAIN + NFILT, 256, 0, stream>>>(
        W, dmap, A_p, A_d, wmax, xbar_pre, Xd, Xpost, Vpost, u_pot, u_dep,
        out, W_new, xbar_new, u_pot_new, u_dep_new);
}